// Round 9
// baseline (279.155 us; speedup 1.0000x reference)
//
#include <hip/hip_runtime.h>
#include <hip/hip_fp16.h>

#define N_NODES   100000
#define D_DIM     16
#define NFILT     8
#define KOUT      128
#define NNZ_CNT   1600000

#define CBITS     8
#define CROWS     256                                  // rows per coarse bucket
#define NCB       ((N_NODES + CROWS - 1) / CROWS)      // 391 buckets
#define CAP       5120                                 // record slots per bucket (mean 4092, sigma 64)
#define EPB       2048                                 // edges per binA block
#define NBLKA     ((NNZ_CNT + EPB - 1) / EPB)          // 782

// fp32 -> bf16 bits with round-to-nearest-even
__device__ __forceinline__ uint f32_to_bf16_bits(float f) {
    uint u = __float_as_uint(f);
    return (u + 0x7FFFu + ((u >> 16) & 1u)) >> 16;
}

// w_wav[n,f] = t^(2^f) - t^(2^(f+1)); fp32 compute, bf16 store (RNE)
__global__ void wav_kernel(const float* __restrict__ eig, ushort* __restrict__ wavb) {
    int n = blockIdx.x * blockDim.x + threadIdx.x;
    if (n >= N_NODES) return;
    float cur = expf(-eig[n]);
    uint pk[4];
#pragma unroll
    for (int h = 0; h < 4; ++h) {
        float nx0 = cur * cur;
        float w0 = cur - nx0;
        float nx1 = nx0 * nx0;
        float w1 = nx0 - nx1;
        cur = nx1;
        pk[h] = f32_to_bf16_bits(w0) | (f32_to_bf16_bits(w1) << 16);
    }
    *(uint4*)(wavb + (size_t)n * NFILT) = make_uint4(pk[0], pk[1], pk[2], pk[3]);
}

// Pass 1: LTxH[c, j] += v[e] * {x[r,j], x[r,j+8]}  as one packed-f16 atomic.
// 8 threads/edge, 12.8M pk-atomics (vs 25.6M f32) — atomic-throughput bound.
__global__ void scatter1_kernel(const float* __restrict__ x,
                                const int* __restrict__ rows,
                                const int* __restrict__ cols,
                                const float* __restrict__ v,
                                __half2* __restrict__ LTxH) {
    long long idx = (long long)blockIdx.x * blockDim.x + threadIdx.x;
    if (idx >= (long long)NNZ_CNT * 8) return;
    int e = (int)(idx >> 3);
    int j = (int)(idx & 7);
    int r = rows[e];
    int c = cols[e];
    float vv = v[e];
    float a = vv * x[(size_t)r * D_DIM + j];
    float b = vv * x[(size_t)r * D_DIM + j + 8];
    unsafeAtomicAdd(&LTxH[(size_t)c * NFILT + j], __floats2half2_rn(a, b));
}

// binA v2: count -> reserve block-private span per bucket -> direct global
// scatter. No scan, no LDS record buffer, no copy-out loop.
// Record: x = ((row&255)<<17) | col, y = bits of v.
__global__ __launch_bounds__(512) void binA_kernel(const int* __restrict__ rows,
                                                   const int* __restrict__ cols,
                                                   const float* __restrict__ v,
                                                   int* __restrict__ gcur,
                                                   int2* __restrict__ regA) {
    __shared__ int cnt[NCB];
    __shared__ int gbase[NCB];
    int tid = threadIdx.x;
    int e0 = blockIdx.x * EPB;
    int nE = NNZ_CNT - e0; if (nE > EPB) nE = EPB;

    for (int i = tid; i < NCB; i += 512) cnt[i] = 0;
    __syncthreads();
    for (int i = tid; i < nE; i += 512)
        atomicAdd(&cnt[rows[e0 + i] >> CBITS], 1);
    __syncthreads();
    for (int i = tid; i < NCB; i += 512) {
        int cv = cnt[i];
        gbase[i] = cv ? atomicAdd(&gcur[i], cv) : 0;
        cnt[i] = 0;   // becomes block-local cursor
    }
    __syncthreads();
    for (int i = tid; i < nE; i += 512) {
        int r = rows[e0 + i], c = cols[e0 + i];
        int b = r >> CBITS;
        int pos = atomicAdd(&cnt[b], 1);
        regA[(size_t)b * CAP + gbase[b] + pos] =
            make_int2(((r & (CROWS - 1)) << 17) | c, __float_as_int(v[e0 + i]));
    }
}

// binB: one block per bucket; LDS count+scan over 256 rows; row-sorted records
// written back IN PLACE (block-private window); offs2[row] = {start, end}.
__global__ __launch_bounds__(512) void binB_kernel(const int* __restrict__ gcur,
                                                   int2* __restrict__ regA,
                                                   int2* __restrict__ offs2) {
    __shared__ int2 rec[CAP];
    __shared__ int cnt[CROWS];
    __shared__ int sc[CROWS];
    int tid = threadIdx.x;
    int b = blockIdx.x;
    int nb = gcur[b]; if (nb > CAP) nb = CAP;
    size_t base = (size_t)b * CAP;

    if (tid < CROWS) cnt[tid] = 0;
    __syncthreads();
    for (int i = tid; i < nb; i += 512) {
        int2 r = regA[base + i];
        rec[i] = r;
        atomicAdd(&cnt[r.x >> 17], 1);
    }
    __syncthreads();

    int cv = (tid < CROWS) ? cnt[tid] : 0;
    if (tid < CROWS) sc[tid] = cv;
    __syncthreads();
    for (int off = 1; off < CROWS; off <<= 1) {
        int t = (tid < CROWS && tid >= off) ? sc[tid - off] : 0;
        __syncthreads();
        if (tid < CROWS) sc[tid] += t;
        __syncthreads();
    }
    if (tid < CROWS) {
        int st = sc[tid] - cv;
        int row = b * CROWS + tid;
        if (row < N_NODES)
            offs2[row] = make_int2((int)base + st, (int)base + st + cv);
        cnt[tid] = st;   // becomes cursor
    }
    __syncthreads();

    for (int i = tid; i < nb; i += 512) {
        int2 r = rec[i];
        int p = atomicAdd(&cnt[r.x >> 17], 1);
        regA[base + p] = make_int2(r.x & 0x1FFFF, r.y);
    }
}

// Pass 2 gather: one wave per row; lane owns outputs (lane) and (lane+64).
// Operands: LTxH __half2 = {f16 d, f16 d+8}, wav bf16.
__global__ __launch_bounds__(256) void gather2_kernel(const int2* __restrict__ offs2,
                                                      const int2* __restrict__ ep,
                                                      const __half2* __restrict__ LTxH,
                                                      const ushort* __restrict__ wavb,
                                                      float* __restrict__ out) {
    int wave = (int)(((long long)blockIdx.x * blockDim.x + threadIdx.x) >> 6);
    if (wave >= N_NODES) return;
    int lane = threadIdx.x & 63;
    int r = wave;
    int d0 = lane >> 3;        // pair index 0..7
    int f  = lane & 7;         // 0..7
    int2 se = offs2[r];
    int i = se.x, end = se.y;
    float acc0 = 0.f, acc1 = 0.f;
    for (; i + 4 <= end; i += 4) {
        int2 e0 = ep[i], e1 = ep[i + 1], e2 = ep[i + 2], e3 = ep[i + 3];
        __half2 h0 = LTxH[e0.x * NFILT + d0];
        __half2 h1 = LTxH[e1.x * NFILT + d0];
        __half2 h2 = LTxH[e2.x * NFILT + d0];
        __half2 h3 = LTxH[e3.x * NFILT + d0];
        uint w0 = wavb[e0.x * NFILT + f];
        uint w1 = wavb[e1.x * NFILT + f];
        uint w2 = wavb[e2.x * NFILT + f];
        uint w3 = wavb[e3.x * NFILT + f];
        float2 l0 = __half22float2(h0);
        float2 l1 = __half22float2(h1);
        float2 l2 = __half22float2(h2);
        float2 l3 = __half22float2(h3);
        float vw0 = __int_as_float(e0.y) * __uint_as_float(w0 << 16);
        float vw1 = __int_as_float(e1.y) * __uint_as_float(w1 << 16);
        float vw2 = __int_as_float(e2.y) * __uint_as_float(w2 << 16);
        float vw3 = __int_as_float(e3.y) * __uint_as_float(w3 << 16);
        acc0 = fmaf(vw0, l0.x, acc0); acc1 = fmaf(vw0, l0.y, acc1);
        acc0 = fmaf(vw1, l1.x, acc0); acc1 = fmaf(vw1, l1.y, acc1);
        acc0 = fmaf(vw2, l2.x, acc0); acc1 = fmaf(vw2, l2.y, acc1);
        acc0 = fmaf(vw3, l3.x, acc0); acc1 = fmaf(vw3, l3.y, acc1);
    }
    for (; i < end; ++i) {
        int2 e = ep[i];
        float2 l = __half22float2(LTxH[e.x * NFILT + d0]);
        uint w = wavb[e.x * NFILT + f];
        float vw = __int_as_float(e.y) * __uint_as_float(w << 16);
        acc0 = fmaf(vw, l.x, acc0); acc1 = fmaf(vw, l.y, acc1);
    }
    out[(size_t)r * KOUT + lane]      = acc0;
    out[(size_t)r * KOUT + 64 + lane] = acc1;
}

extern "C" void kernel_launch(void* const* d_in, const int* in_sizes, int n_in,
                              void* d_out, int out_size, void* d_ws, size_t ws_size,
                              hipStream_t stream) {
    const float* x      = (const float*)d_in[0];
    const int*   L_rows = (const int*)  d_in[1];
    const int*   L_cols = (const int*)  d_in[2];
    const float* L_v    = (const float*)d_in[3];
    const float* eig    = (const float*)d_in[4];
    float* out = (float*)d_out;

    // workspace layout (~22 MB), 8B-aligned segments
    __half2* LTxH  = (__half2*)d_ws;                           // [N*8]      3.2 MB (f16-pair accum)
    ushort*  wavb  = (ushort*)(LTxH + (size_t)N_NODES * NFILT);// [N*8]      1.6 MB (bf16)
    int2*    offs2 = (int2*)(wavb + (size_t)N_NODES * NFILT);  // [N]        0.8 MB
    int2*    regA  = offs2 + N_NODES;                          // [NCB*CAP] 16.0 MB
    int*     gcur  = (int*)(regA + (size_t)NCB * CAP);         // [NCB]

    hipMemsetAsync(LTxH, 0, (size_t)N_NODES * NFILT * sizeof(__half2), stream);
    hipMemsetAsync(gcur, 0, (size_t)NCB * sizeof(int), stream);

    wav_kernel<<<(N_NODES + 255) / 256, 256, 0, stream>>>(eig, wavb);

    // Pass 1 (packed-f16 atomic scatter)
    {
        long long total = (long long)NNZ_CNT * 8;
        scatter1_kernel<<<(int)((total + 255) / 256), 256, 0, stream>>>(x, L_rows, L_cols, L_v, LTxH);
    }

    // Two-level block-local sort
    binA_kernel<<<NBLKA, 512, 0, stream>>>(L_rows, L_cols, L_v, gcur, regA);
    binB_kernel<<<NCB, 512, 0, stream>>>(gcur, regA, offs2);

    // Pass 2 (gather, no atomics)
    {
        long long threads = (long long)N_NODES * 64;   // one wave per row
        gather2_kernel<<<(int)((threads + 255) / 256), 256, 0, stream>>>(offs2, regA, LTxH, wavb, out);
    }
}